// Round 3
// baseline (125.421 us; speedup 1.0000x reference)
//
#include <hip/hip_runtime.h>
#include <math.h>

#define NTOT 131072
#define NSIG 64
#define SEGL 2048
#define NIN 256
#define CHUNK 256
#define NBLK (NTOT / CHUNK)   // 512 blocks, 2 per CU

// One fused kernel. 512 blocks x 256 threads; block bx handles outputs
// [seg*2048 + M0, +256) with seg = bx>>3, M0 = (bx&7)*256.
// Phases: zero S / stage x -> MLP sigma (redundant per block; W1 L2-resident)
//   -> truncated window (only |d|<=D taps; taps beyond 12|sigma|+4 contribute
//      <= 2048*exp(-72) ~ 1e-28 to Z and out - negligible vs 9.2e-2 threshold)
//   -> matvec of core 256 + 2D halo columns, single interleaved n-loop
//      (col clo+t always, col clo+t+256 exec-mask-predicated; no thin-pass
//       latency tail) -> truncated conv from LDS -> store.
__global__ __launch_bounds__(256) void k_fused(
    const float* __restrict__ x,  const float* __restrict__ W1,
    const float* __restrict__ b1, const float* __restrict__ W2,
    const float* __restrict__ b2, const float* __restrict__ W3,
    const float* __restrict__ b3, float* __restrict__ out)
{
  __shared__ float xl[NIN];     // x staged
  __shared__ float sl[256];     // swish hidden
  __shared__ float red[4];
  __shared__ float bc[2];       // sigma, Z
  __shared__ float S[2560];     // y slice, seg coord = sbase + idx
  __shared__ float Wl[SEGL];    // window (only [1024+dlo, 1024+dhi] valid)

  const int t = threadIdx.x;
  // bijective XCD swizzle: 512 blocks / 8 XCDs -> 64 consecutive per XCD
  const int bx0 = (int)blockIdx.x;
  const int bx = ((bx0 & 7) << 6) | (bx0 >> 3);
  const int seg = bx >> 3;
  const int M0 = (bx & 7) << 8;

  // zero padded y slice (zero padding == "same" boundary)
  #pragma unroll
  for (int j = 0; j < 10; ++j) S[t + j * 256] = 0.0f;
  xl[t] = x[t];
  __syncthreads();

  // ---- MLP: s = swish(x@W1 + b1), hidden unit t per thread ----
  float acc = b1[t];
  #pragma unroll 32
  for (int n = 0; n < NIN; ++n) acc += xl[n] * W1[n * 256 + t];
  sl[t] = acc / (1.0f + expf(-acc));
  __syncthreads();

  // ---- sigma = s @ W2[:,seg] + b2[seg] ----
  float v = sl[t] * W2[t * NSIG + seg];
  #pragma unroll
  for (int o = 32; o > 0; o >>= 1) v += __shfl_down(v, o, 64);
  const int lane = t & 63, wid = t >> 6;
  if (lane == 0) red[wid] = v;
  __syncthreads();
  if (t == 0) bc[0] = red[0] + red[1] + red[2] + red[3] + b2[seg];
  __syncthreads();
  const float sig = bc[0];

  // ---- truncated gaussian window ----
  const float inv2 = 1.0f / (2.0f * sig * sig);
  const float Df = 12.0f * fabsf(sig) + 4.0f;
  const int D = (Df >= 1024.0f) ? 1024 : (int)Df;
  const int dlo = -D;                       // D <= 1024
  const int dhi = (D < 1023) ? D : 1023;
  const int cnt = dhi - dlo + 1;

  float zp = 0.0f;
  for (int i = t; i < cnt; i += 256) {
    const float d = (float)(dlo + i);
    const float e = expf(-d * d * inv2);
    Wl[1024 + dlo + i] = e;
    zp += e;
  }
  v = zp;
  #pragma unroll
  for (int o = 32; o > 0; o >>= 1) v += __shfl_down(v, o, 64);
  if (lane == 0) red[wid] = v;
  __syncthreads();
  if (t == 0) bc[1] = red[0] + red[1] + red[2] + red[3];
  __syncthreads();
  const float iZ = 1.0f / bc[1];
  for (int i = t; i < cnt; i += 256) Wl[1024 + dlo + i] *= iZ;

  // ---- matvec: y cols [clo, chi) of this segment into S ----
  int clo = M0 - 1 - D; if (clo < 0) clo = 0;
  int chi = M0 + CHUNK + D; if (chi > SEGL) chi = SEGL;
  const int segbase = seg * SEGL;
  const int sbase = M0 - 1026;

  const int c0 = clo + t;          // always < chi (chi-clo >= 257)
  const int c1 = c0 + 256;
  const bool h1 = (c1 < chi);
  const float* p0 = W3 + segbase + c0;
  float a0 = b3[segbase + c0];
  float a1 = h1 ? b3[segbase + c1] : 0.0f;
  #pragma unroll 16
  for (int n = 0; n < NIN; ++n) {
    const float xv = xl[n];
    a0 = fmaf(xv, __builtin_nontemporal_load(p0 + (size_t)n * NTOT), a0);
    if (h1)
      a1 = fmaf(xv, __builtin_nontemporal_load(p0 + (size_t)n * NTOT + 256), a1);
  }
  S[c0 - sbase] = a0;
  if (h1) S[c1 - sbase] = a1;
  // rare remainder (only when D > ~255; correctness path)
  for (int c = clo + 512 + t; c < chi; c += 256) {
    const float* p = W3 + segbase + c;
    float a = b3[segbase + c];
    #pragma unroll 16
    for (int n = 0; n < NIN; ++n)
      a = fmaf(xl[n], __builtin_nontemporal_load(p + (size_t)n * NTOT), a);
    S[c - sbase] = a;
  }
  __syncthreads();

  // ---- truncated conv: out[M0+t] = sum_d Wl[1024+d] * seg[M0+t-1-d] ----
  float a = 0.0f;
  for (int d = dlo; d <= dhi; ++d)
    a = fmaf(Wl[1024 + d], S[t + 1025 - d], a);  // broadcast + stride-1
  out[segbase + M0 + t] = a;
}

extern "C" void kernel_launch(void* const* d_in, const int* in_sizes, int n_in,
                              void* d_out, int out_size, void* d_ws, size_t ws_size,
                              hipStream_t stream) {
  const float* x  = (const float*)d_in[0];
  const float* W1 = (const float*)d_in[1];
  const float* b1 = (const float*)d_in[2];
  const float* W2 = (const float*)d_in[3];
  const float* b2 = (const float*)d_in[4];
  const float* W3 = (const float*)d_in[5];
  const float* b3 = (const float*)d_in[6];
  float* out = (float*)d_out;

  hipLaunchKernelGGL(k_fused, dim3(NBLK), dim3(256), 0, stream,
                     x, W1, b1, W2, b2, W3, b3, out);
}

// Round 4
// 39.818 us; speedup vs baseline: 3.1498x; 3.1498x over previous
//
#include <hip/hip_runtime.h>
#include <math.h>

#define NTOT 131072
#define NSIG 64
#define SEGL 2048
#define NIN 256
#define CHUNK 256
#define NBLK (NTOT / CHUNK)   // 512 blocks, 2 per CU

// One fused kernel. 512 blocks x 256 threads; block bx handles outputs
// [seg*2048 + M0, +256), seg = bx>>3, M0 = (bx&7)*256.
// Order: stage x -> CORE matvec (col M0+t, branch-free, 83% of HBM traffic,
// starts immediately) -> tiny MLP -> sigma -> truncated window -> HALO matvec
// (clamped indices, branch-free) -> truncated conv -> store.
// Truncation: taps beyond |d| = 12|sigma|+4 are exp(<-72) == 0 in f32 and the
// normalizer Z >= 1 (peak tap exp(0)=1), so truncation error ~1e-28 absolute.
__global__ __launch_bounds__(256) void k_fused(
    const float* __restrict__ x,  const float* __restrict__ W1,
    const float* __restrict__ b1, const float* __restrict__ W2,
    const float* __restrict__ b2, const float* __restrict__ W3,
    const float* __restrict__ b3, float* __restrict__ out)
{
  __shared__ float xl[NIN];     // x staged
  __shared__ float sl[256];     // swish hidden
  __shared__ float red[4];
  __shared__ float bc[2];       // sigma, Z
  __shared__ float S[2560];     // y slice; seg coord = sbase + idx
  __shared__ float Wl[SEGL];    // window (only [1024+dlo, 1024+dhi] written)

  const int t = threadIdx.x;
  // XCD swizzle: consecutive bx (neighboring chunks) on the same XCD,
  // so halo columns hit the L2 lines of neighbors' core columns.
  const int bx0 = (int)blockIdx.x;
  const int bx = ((bx0 & 7) << 6) | (bx0 >> 3);
  const int seg = bx >> 3;
  const int M0 = (bx & 7) << 8;
  const int segbase = seg * SEGL;
  const int sbase = M0 - 1026;

  #pragma unroll
  for (int j = 0; j < 10; ++j) S[t + j * 256] = 0.0f;  // zero padding
  xl[t] = x[t];
  __syncthreads();

  // ---- CORE matvec: y col M0+t (always needed, no deps, branch-free) ----
  {
    const float* p = W3 + segbase + M0 + t;
    float a = b3[segbase + M0 + t];
    #pragma unroll 16
    for (int n = 0; n < NIN; ++n)
      a = fmaf(xl[n], p[(size_t)n * NTOT], a);
    S[t + 1026] = a;   // (M0+t) - sbase
  }

  // ---- MLP: s = swish(x@W1 + b1) ----
  float acc = b1[t];
  #pragma unroll 16
  for (int n = 0; n < NIN; ++n) acc = fmaf(xl[n], W1[n * 256 + t], acc);
  sl[t] = acc / (1.0f + expf(-acc));
  __syncthreads();

  // ---- sigma = s @ W2[:,seg] + b2[seg] ----
  float v = sl[t] * W2[t * NSIG + seg];
  #pragma unroll
  for (int o = 32; o > 0; o >>= 1) v += __shfl_down(v, o, 64);
  const int lane = t & 63, wid = t >> 6;
  if (lane == 0) red[wid] = v;
  __syncthreads();
  if (t == 0) bc[0] = red[0] + red[1] + red[2] + red[3] + b2[seg];
  __syncthreads();
  const float sig = bc[0];

  // ---- truncated gaussian window ----
  const float inv2 = 1.0f / (2.0f * sig * sig);
  const float Df = 12.0f * fabsf(sig) + 4.0f;
  const int D = (Df >= 1024.0f) ? 1024 : (int)Df;
  const int dlo = -D;
  const int dhi = (D < 1023) ? D : 1023;
  const int cnt = dhi - dlo + 1;

  float zp = 0.0f;
  for (int i = t; i < cnt; i += 256) {
    const float d = (float)(dlo + i);
    const float e = expf(-d * d * inv2);
    Wl[1024 + dlo + i] = e;
    zp += e;
  }
  v = zp;
  #pragma unroll
  for (int o = 32; o > 0; o >>= 1) v += __shfl_down(v, o, 64);
  if (lane == 0) red[wid] = v;
  __syncthreads();
  if (t == 0) bc[1] = red[0] + red[1] + red[2] + red[3];
  __syncthreads();
  const float iZ = 1.0f / bc[1];
  for (int i = t; i < cnt; i += 256) Wl[1024 + dlo + i] *= iZ;

  // ---- HALO matvec: cols [clo,M0) and [M0+256,chi), clamped branch-free ----
  int clo = M0 - 1 - D; if (clo < 0) clo = 0;
  int chi = M0 + CHUNK + D; if (chi > SEGL) chi = SEGL;
  const int hlo = M0 - clo;             // halo count below core
  const int hcnt = hlo + (chi - (M0 + CHUNK));
  {
    const int h = (t < hcnt) ? t : (hcnt - 1);   // clamp: dup loads broadcast,
    const int c = (h < hlo) ? (clo + h)          // dup LDS writes same value
                            : (M0 + CHUNK + (h - hlo));
    const float* p = W3 + segbase + c;
    float a = b3[segbase + c];
    #pragma unroll 16
    for (int n = 0; n < NIN; ++n)
      a = fmaf(xl[n], p[(size_t)n * NTOT], a);
    S[c - sbase] = a;
  }
  // cold path: only if D > ~252 (|sigma| > 20; never for this init scale)
  for (int h = 256 + t; h < hcnt; h += 256) {
    const int c = (h < hlo) ? (clo + h) : (M0 + CHUNK + (h - hlo));
    const float* p = W3 + segbase + c;
    float a = b3[segbase + c];
    #pragma unroll 16
    for (int n = 0; n < NIN; ++n)
      a = fmaf(xl[n], p[(size_t)n * NTOT], a);
    S[c - sbase] = a;
  }
  __syncthreads();

  // ---- truncated conv: out[M0+t] = sum_d Wl[1024+d] * seg[M0+t-1-d] ----
  float a = 0.0f;
  for (int d = dlo; d <= dhi; ++d)
    a = fmaf(Wl[1024 + d], S[t + 1025 - d], a);  // broadcast + stride-1
  out[segbase + M0 + t] = a;
}

extern "C" void kernel_launch(void* const* d_in, const int* in_sizes, int n_in,
                              void* d_out, int out_size, void* d_ws, size_t ws_size,
                              hipStream_t stream) {
  const float* x  = (const float*)d_in[0];
  const float* W1 = (const float*)d_in[1];
  const float* b1 = (const float*)d_in[2];
  const float* W2 = (const float*)d_in[3];
  const float* b2 = (const float*)d_in[4];
  const float* W3 = (const float*)d_in[5];
  const float* b3 = (const float*)d_in[6];
  float* out = (float*)d_out;

  hipLaunchKernelGGL(k_fused, dim3(NBLK), dim3(256), 0, stream,
                     x, W1, b1, W2, b2, W3, b3, out);
}

// Round 5
// 31.831 us; speedup vs baseline: 3.9402x; 1.2509x over previous
//
#include <hip/hip_runtime.h>
#include <math.h>

#define NTOT 131072
#define NSIG 64
#define SEGL 2048
#define NIN 256

// ws layout (bytes):
//   [0, 524288)        y[131072] f32
//   [524288, 1048576)  w_all[64][2048] f32 (normalized window; only the
//                      [1024-D, 1024+min(D,1023)] taps are written/read)
//   [1048576, 1048832) Dv[64] int
//
// Truncation: taps beyond |d| = 12|sigma|+4 are exp(<-72) == 0 in f32 and
// Z >= 1 (peak tap exp(0)=1), so truncation error ~1e-28 absolute.

// ---------------------------------------------------------------------------
// K1: y = x@W3 + b3, each column computed exactly ONCE (no halo, no overfetch,
// branch-free stream). 512 blocks x 256 threads, col = bx*256+t.
// Blocks bx0 < 64 are "duty" blocks: they fold the MLP dot (W1, L2-resident)
// into the SAME unrolled loop as the W3 stream (hidden under HBM latency),
// then compute sigma -> normalized truncated window -> ws for segment bx0.
// ---------------------------------------------------------------------------
__global__ __launch_bounds__(256) void k_y(
    const float* __restrict__ x,  const float* __restrict__ W1,
    const float* __restrict__ b1, const float* __restrict__ W2,
    const float* __restrict__ b2, const float* __restrict__ W3,
    const float* __restrict__ b3, float* __restrict__ y,
    float* __restrict__ w_all, int* __restrict__ Dv)
{
  __shared__ float xl[NIN];
  __shared__ float sl[256];
  __shared__ float red[4];
  __shared__ float bc[2];

  const int t = threadIdx.x;
  const int bx0 = (int)blockIdx.x;
  // bijective XCD swizzle: 64 consecutive chunks per XCD
  const int bx = ((bx0 & 7) << 6) | (bx0 >> 3);
  const int col = (bx << 8) + t;

  xl[t] = x[t];
  __syncthreads();

  const float* p = W3 + col;
  float a = b3[col];

  if (bx0 < NSIG) {
    // ---- duty block: matvec + MLP in one loop ----
    float am = b1[t];
    #pragma unroll 16
    for (int n = 0; n < NIN; ++n) {
      const float xv = xl[n];
      a  = fmaf(xv, p[(size_t)n * NTOT], a);
      am = fmaf(xv, W1[n * 256 + t], am);
    }
    y[col] = a;
    sl[t] = am / (1.0f + expf(-am));
    __syncthreads();

    const int seg = bx0;
    float v = sl[t] * W2[t * NSIG + seg];
    #pragma unroll
    for (int o = 32; o > 0; o >>= 1) v += __shfl_down(v, o, 64);
    const int lane = t & 63, wid = t >> 6;
    if (lane == 0) red[wid] = v;
    __syncthreads();
    if (t == 0) bc[0] = red[0] + red[1] + red[2] + red[3] + b2[seg];
    __syncthreads();
    const float sig = bc[0];

    const float inv2 = 1.0f / (2.0f * sig * sig);
    const float Df = 12.0f * fabsf(sig) + 4.0f;
    const int D = (Df >= 1024.0f) ? 1024 : (int)Df;
    const int dlo = -D;
    const int dhi = (D < 1023) ? D : 1023;
    const int cnt = dhi - dlo + 1;

    float zp = 0.0f;
    for (int i = t; i < cnt; i += 256) {
      const float d = (float)(dlo + i);
      const float e = expf(-d * d * inv2);
      w_all[seg * SEGL + 1024 + dlo + i] = e;   // unnormalized for now
      zp += e;
    }
    v = zp;
    #pragma unroll
    for (int o = 32; o > 0; o >>= 1) v += __shfl_down(v, o, 64);
    if (lane == 0) red[wid] = v;
    __syncthreads();
    if (t == 0) bc[1] = red[0] + red[1] + red[2] + red[3];
    __syncthreads();
    const float iZ = 1.0f / bc[1];
    for (int i = t; i < cnt; i += 256)
      w_all[seg * SEGL + 1024 + dlo + i] *= iZ;
    if (t == 0) Dv[seg] = D;
  } else {
    // ---- pure stream ----
    #pragma unroll 16
    for (int n = 0; n < NIN; ++n)
      a = fmaf(xl[n], p[(size_t)n * NTOT], a);
    y[col] = a;
  }
}

// ---------------------------------------------------------------------------
// K2: truncated "same" conv. 512 blocks x 256 threads; block bx handles
// outputs [seg*2048 + M0, +256), seg = bx>>3, M0 = (bx&7)*256.
// y (512 KB) and windows are L2/L3-resident from K1.
// out[m] = sum_d w[1024+d] * seg[m-1-d], d in [-D, min(D,1023)]
// ---------------------------------------------------------------------------
__global__ __launch_bounds__(256) void k_conv(
    const float* __restrict__ y, const float* __restrict__ w_all,
    const int* __restrict__ Dv, float* __restrict__ out)
{
  __shared__ float S[2560];   // y slice, seg coord = sbase + idx, zero-padded
  __shared__ float Wl[SEGL];

  const int t = threadIdx.x;
  const int bx0 = (int)blockIdx.x;
  const int bx = ((bx0 & 7) << 6) | (bx0 >> 3);   // same swizzle as K1
  const int seg = bx >> 3;
  const int M0 = (bx & 7) << 8;
  const int sbase = M0 - 1026;

  const int D = Dv[seg];
  const int dlo = -D;
  const int dhi = (D < 1023) ? D : 1023;
  const int cnt = dhi - dlo + 1;

  for (int i = t; i < cnt; i += 256)
    Wl[1024 + dlo + i] = w_all[seg * SEGL + 1024 + dlo + i];

  #pragma unroll
  for (int j = 0; j < 10; ++j) {
    const int i = t + j * 256;
    const int g = sbase + i;
    S[i] = (g >= 0 && g < SEGL) ? y[seg * SEGL + g] : 0.0f;
  }
  __syncthreads();

  float a = 0.0f;
  for (int d = dlo; d <= dhi; ++d)
    a = fmaf(Wl[1024 + d], S[t + 1025 - d], a);   // broadcast + stride-1
  out[seg * SEGL + M0 + t] = a;
}

// ---------------------------------------------------------------------------
extern "C" void kernel_launch(void* const* d_in, const int* in_sizes, int n_in,
                              void* d_out, int out_size, void* d_ws, size_t ws_size,
                              hipStream_t stream) {
  const float* x  = (const float*)d_in[0];
  const float* W1 = (const float*)d_in[1];
  const float* b1 = (const float*)d_in[2];
  const float* W2 = (const float*)d_in[3];
  const float* b2 = (const float*)d_in[4];
  const float* W3 = (const float*)d_in[5];
  const float* b3 = (const float*)d_in[6];
  float* out = (float*)d_out;

  char* ws = (char*)d_ws;
  float* y     = (float*)(ws);
  float* w_all = (float*)(ws + 524288);
  int*   Dv    = (int*)  (ws + 1048576);

  hipLaunchKernelGGL(k_y, dim3(512), dim3(256), 0, stream,
                     x, W1, b1, W2, b2, W3, b3, y, w_all, Dv);
  hipLaunchKernelGGL(k_conv, dim3(512), dim3(256), 0, stream,
                     y, w_all, Dv, out);
}